// Round 4
// baseline (204.049 us; speedup 1.0000x reference)
//
#include <hip/hip_runtime.h>
#include <math.h>

#define NN 100000
#define DI 64
#define DH 128
#define DO 40

#define NBUCK 512
#define NPB 196          // nodes per bucket: 512*196 = 100352 >= 100000
#define CAP 3712         // bucket capacity: mean 3125 + ~10.5 sigma
#define CAPP 5120        // padded col capacity: CAP + NPB*7 = 5084, rounded to 64
#define EPB 4096         // edges per scatter block
#define TPB_S 512        // threads per scatter/setup block
#define KE (EPB / TPB_S) // edges per thread = 8

typedef __attribute__((ext_vector_type(8))) short bf16x8;
typedef __attribute__((ext_vector_type(4))) float f32x4;
typedef __attribute__((ext_vector_type(2))) float f32x2;

__device__ __forceinline__ unsigned short bf16r(float a) {
    unsigned u = __float_as_uint(a);
    u = (u + 0x7FFF + ((u >> 16) & 1)) >> 16;
    return (unsigned short)u;
}
__device__ __forceinline__ unsigned bf16pair(float a, float b) {
    return (unsigned)bf16r(a) | ((unsigned)bf16r(b) << 16);
}
__device__ __forceinline__ float bflo(unsigned u) { return __uint_as_float(u << 16); }
__device__ __forceinline__ float bfhi(unsigned u) { return __uint_as_float(u & 0xFFFF0000u); }

// ---------- fused: scatter blocks [0,nbe) + setup blocks [nbe, nbe+nsetup) ----------
__global__ __launch_bounds__(TPB_S) void setup_scatter_kernel(
        const float* __restrict__ x, const float* __restrict__ W1l,
        const float* __restrict__ W1r, const float* __restrict__ W2l,
        const float* __restrict__ W2r,
        unsigned* __restrict__ xb, unsigned short* __restrict__ WB1,
        unsigned short* __restrict__ WB2, unsigned* __restrict__ p2,
        const int* __restrict__ src, const int* __restrict__ dst,
        int* __restrict__ bcur, int* __restrict__ eb,
        int nbe, int E, int N) {
    __shared__ int h[NBUCK];
    int t = threadIdx.x;
    if ((int)blockIdx.x < nbe) {
        // ---- bucket scatter: eb[pos] = (local<<17)|src ----
        if (t < NBUCK) h[t] = 0;
        __syncthreads();
        int base = blockIdx.x * EPB;
        int end = base + EPB; if (end > E) end = E;
        int dloc[KE];
#pragma unroll
        for (int k = 0; k < KE; k++) {
            int i = base + t + k * TPB_S;
            dloc[k] = (i < end) ? dst[i] : -1;
        }
#pragma unroll
        for (int k = 0; k < KE; k++)
            if (dloc[k] >= 0) atomicAdd(&h[(unsigned)dloc[k] / NPB], 1);
        __syncthreads();
        if (t < NBUCK) {
            int v = h[t];
            h[t] = v ? (atomicAdd(&bcur[t], v) + t * CAP) : 0;
        }
        __syncthreads();
#pragma unroll
        for (int k = 0; k < KE; k++) {
            int d = dloc[k];
            if (d >= 0) {
                unsigned bk = (unsigned)d / NPB;
                int local = d - (int)bk * NPB;
                int pos = atomicAdd(&h[bk], 1);
                eb[pos] = (local << 17) | src[base + t + k * TPB_S];
            }
        }
    } else {
        // ---- setup: x->bf16, weight packs, p2 dummy row ----
        int idx = (blockIdx.x - nbe) * TPB_S + t;
        if (idx < (N + 1) * 32) {
            if (idx < N * 32) {
                float2 f = ((const float2*)x)[idx];
                xb[idx] = bf16pair(f.x, f.y);
            } else {
                xb[idx] = 0;          // dummy row N of xb
            }
        }
        if (idx < 16384) {
            int j = idx & 7, lane = (idx >> 3) & 63, ks = (idx >> 9) & 3, nt = idx >> 11;
            int k = ks * 32 + (lane >> 4) * 8 + j;
            int n = nt * 16 + (lane & 15);
            float v = (k < DI) ? W1l[n * DI + k] : W1r[n * DI + (k - DI)];
            WB1[idx] = bf16r(v);
        }
        if (idx >= 16384 && idx < 16384 + 10240) {
            int idx2 = idx - 16384;
            int j = idx2 & 7, lane = (idx2 >> 3) & 63, ks = (idx2 >> 9) & 3, nt = idx2 >> 11;
            int k = ks * 32 + (lane >> 4) * 8 + j;
            int n = nt * 16 + (lane & 15);
            float v = (n < DO) ? W2l[n * DH + k] : W2r[(n - DO) * DH + k];
            WB2[idx2] = bf16r(v);
        }
        if (idx < 10) p2[(size_t)N * 10 + idx] = 0;   // dummy fp8 row N (decodes to 0)
    }
}

// ---------- fill: per bucket -> rowptr/cnt/inv + col padded to x8 with dummy NN ----------
__global__ __launch_bounds__(256) void bucket_fill_kernel(const int* __restrict__ eb,
                                                          const int* __restrict__ bend,
                                                          int* __restrict__ rowptr,
                                                          int* __restrict__ cntg,
                                                          float* __restrict__ inv,
                                                          int* __restrict__ col, int N) {
    __shared__ int scnt[256];
    __shared__ int scur[256];
    __shared__ int sbase[256];
    int b = blockIdx.x, t = threadIdx.x;
    int ebeg = b * CAP, eend = ebeg + bend[b];   // bend holds counts
    scnt[t] = 0;
    __syncthreads();
    for (int i = ebeg + t; i < eend; i += 256)
        atomicAdd(&scnt[eb[i] >> 17], 1);
    __syncthreads();
    int myc = scnt[t];
    int pc = (myc + 7) & ~7;                      // pad to x8 for 8-wide gathers
    scnt[t] = pc;
    __syncthreads();
    for (int off = 1; off < 256; off <<= 1) {
        int tmp = (t >= off) ? scnt[t - off] : 0;
        __syncthreads();
        scnt[t] += tmp;
        __syncthreads();
    }
    int excl = scnt[t] - pc;
    int base = b * CAPP + excl;
    int node = b * NPB + t;
    if (t < NPB && node < N) {
        rowptr[node] = base;
        cntg[node] = myc;
        inv[node] = 1.0f / (float)(myc > 0 ? myc : 1);
    }
    scur[t] = base;
    sbase[t] = base;
    __syncthreads();
    for (int i = ebeg + t; i < eend; i += 256) {
        int pk = eb[i];
        int pos = atomicAdd(&scur[pk >> 17], 1);
        col[pos] = pk & 0x1FFFF;
    }
    __syncthreads();
    if (t < NPB) {
        int bs = sbase[t];
        for (int i = myc; i < pc; i++) col[bs + i] = NN;
    }
}

// ---------- fused agg1 + GEMM1 + GEMM2: BARRIER-FREE, wave-private rows ----------
// Phase A: 16 lanes/node, 8-wide uint2 gather (32 outstanding reqs/wave, VGPR<=64).
// Phase B: GEMM1 h=relu(A@Wcat1+b1), in place.
// Phase C: GEMM2 -> p2 (fp8, staged via float alias of own sh rows) + selfp.
__global__ __launch_bounds__(256) void agg_gemm12_kernel(
        const unsigned* __restrict__ xb, const int* __restrict__ rowptr,
        const int* __restrict__ cnt, const float* __restrict__ inv,
        const int* __restrict__ col,
        const unsigned short* __restrict__ WB1, const float* __restrict__ b1,
        const unsigned short* __restrict__ WB2, const float* __restrict__ b2,
        unsigned* __restrict__ p2, float* __restrict__ selfp, int N) {
    __shared__ unsigned short sh[64][136];   // A-tile -> h-tile -> f32 stage (aliased)
    int t = threadIdx.x;
    int w = t >> 6, lane = t & 63;
    int lw = w * 16;
    int sub = lane >> 4;                     // node slot within wave: 0..3
    int c = lane & 15;                       // feature chunk: 4 bf16 = 8B
    int rbase = blockIdx.x * 64 + lw;

    // ---- Phase A: aggregate wave-private rows (4 passes x 4 nodes) ----
#pragma unroll
    for (int it = 0; it < 4; ++it) {
        int lr = lw + it * 4 + sub;
        int n = blockIdx.x * 64 + lr;
        float a0 = 0.f, a1 = 0.f, a2 = 0.f, a3 = 0.f;
        float invn = 0.f;
        uint2 su = make_uint2(0, 0);
        if (n < N) {
            int beg = rowptr[n], deg = cnt[n];
            int degp = (deg + 7) & ~7;
            for (int i = 0; i < degp; i += 8) {
                int ss[8];
#pragma unroll
                for (int k = 0; k < 8; k++) ss[k] = col[beg + i + k];
                uint2 uu[8];
#pragma unroll
                for (int k = 0; k < 8; k++)
                    uu[k] = *(const uint2*)(xb + (size_t)ss[k] * 32 + c * 2);
#pragma unroll
                for (int k = 0; k < 8; k++) {
                    a0 += bflo(uu[k].x); a1 += bfhi(uu[k].x);
                    a2 += bflo(uu[k].y); a3 += bfhi(uu[k].y);
                }
            }
            invn = inv[n];
            su = *(const uint2*)(xb + (size_t)n * 32 + c * 2);
        }
        uint2 o;
        o.x = bf16pair(a0 * invn, a1 * invn);
        o.y = bf16pair(a2 * invn, a3 * invn);
        *(uint2*)&sh[lr][c * 4] = o;         // agg half (cols 0..63)
        *(uint2*)&sh[lr][64 + c * 4] = su;   // self half (cols 64..127)
    }
    asm volatile("" ::: "memory");

    // ---- Phase B: GEMM1 (reads/writes only own rows) ----
    int quad = lane >> 4, m = lane & 15;
    f32x4 acc[8];
#pragma unroll
    for (int nt = 0; nt < 8; nt++) acc[nt] = (f32x4)(0.f);
#pragma unroll
    for (int ks = 0; ks < 4; ks++) {
        bf16x8 a = *(const bf16x8*)(&sh[lw + m][ks * 32 + quad * 8]);
#pragma unroll
        for (int nt = 0; nt < 8; nt++) {
            bf16x8 b = *(const bf16x8*)(WB1 + ((size_t)(nt * 4 + ks) * 64 + lane) * 8);
            acc[nt] = __builtin_amdgcn_mfma_f32_16x16x32_bf16(a, b, acc[nt], 0, 0, 0);
        }
    }
    asm volatile("" ::: "memory");
#pragma unroll
    for (int nt = 0; nt < 8; nt++) {
        int colj = nt * 16 + m;
        float bj = b1[colj];
#pragma unroll
        for (int r = 0; r < 4; r++) {
            sh[lw + quad * 4 + r][colj] = bf16r(fmaxf(acc[nt][r] + bj, 0.f));
        }
    }
    asm volatile("" ::: "memory");

    // ---- Phase C: GEMM2 ----
    f32x4 acc2[5];
#pragma unroll
    for (int nt = 0; nt < 5; nt++) acc2[nt] = (f32x4)(0.f);
#pragma unroll
    for (int ks = 0; ks < 4; ks++) {
        bf16x8 a = *(const bf16x8*)(&sh[lw + m][ks * 32 + quad * 8]);
#pragma unroll
        for (int nt = 0; nt < 5; nt++) {
            bf16x8 b = *(const bf16x8*)(WB2 + ((size_t)(nt * 4 + ks) * 64 + lane) * 8);
            acc2[nt] = __builtin_amdgcn_mfma_f32_16x16x32_bf16(a, b, acc2[nt], 0, 0, 0);
        }
    }
    asm volatile("" ::: "memory");
    float* stw = (float*)&sh[lw][0];         // 16 rows x 41 f32 = 2624 B <= 4352 B
#pragma unroll
    for (int nt = 0; nt < 5; nt++) {
        int colj = nt * 16 + m;
#pragma unroll
        for (int r = 0; r < 4; r++) {
            int row = rbase + quad * 4 + r;
            float v = acc2[nt][r];
            if (colj < 40) {
                stw[(quad * 4 + r) * 41 + colj] = v;
            } else if (row < N) {
                selfp[(size_t)row * 40 + (colj - 40)] = v + b2[colj - 40];
            }
        }
    }
    asm volatile("" ::: "memory");
    for (int i = lane; i < 160; i += 64) {
        int lr = i / 10, dw = i - lr * 10;
        int grow = rbase + lr;
        if (grow < N) {
            float v0 = stw[lr * 41 + dw * 4 + 0], v1 = stw[lr * 41 + dw * 4 + 1];
            float v2 = stw[lr * 41 + dw * 4 + 2], v3 = stw[lr * 41 + dw * 4 + 3];
            unsigned u = __builtin_amdgcn_cvt_pk_fp8_f32(v0, v1, 0u, false);
            u = __builtin_amdgcn_cvt_pk_fp8_f32(v2, v3, u, true);
            p2[(size_t)grow * 10 + dw] = u;
        }
    }
}

// ---------- agg2 + log_softmax: 8 lanes/node (5 active), edges 8-wide ----------
__global__ void agg2_softmax_kernel(const unsigned* __restrict__ p2,
                                    const float* __restrict__ selfp,
                                    const int* __restrict__ rowptr,
                                    const int* __restrict__ cnt,
                                    const float* __restrict__ inv,
                                    const int* __restrict__ col,
                                    float* __restrict__ out, int N) {
    int n = (blockIdx.x * 256 + threadIdx.x) >> 3;
    int chunk = threadIdx.x & 7;
    if (n >= N) return;
    int beg = rowptr[n], deg = cnt[n];
    int degp = (deg + 7) & ~7;
    bool vc = (chunk < 5);
    float a[8];
#pragma unroll
    for (int j = 0; j < 8; j++) a[j] = 0.f;
    for (int i = 0; i < degp; i += 8) {
        int ss[8];
#pragma unroll
        for (int k = 0; k < 8; k++) ss[k] = col[beg + i + k];
        if (vc) {
            uint2 uu[8];
#pragma unroll
            for (int k = 0; k < 8; k++)
                uu[k] = *(const uint2*)(p2 + (size_t)ss[k] * 10 + chunk * 2);
#pragma unroll
            for (int k = 0; k < 8; k++) {
                f32x2 d;
                d = __builtin_amdgcn_cvt_pk_f32_fp8(uu[k].x, false); a[0] += d.x; a[1] += d.y;
                d = __builtin_amdgcn_cvt_pk_f32_fp8(uu[k].x, true);  a[2] += d.x; a[3] += d.y;
                d = __builtin_amdgcn_cvt_pk_f32_fp8(uu[k].y, false); a[4] += d.x; a[5] += d.y;
                d = __builtin_amdgcn_cvt_pk_f32_fp8(uu[k].y, true);  a[6] += d.x; a[7] += d.y;
            }
        }
    }
    float invn = inv[n];
    float v[8];
    if (vc) {
        float4 s0 = *(const float4*)(selfp + (size_t)n * DO + chunk * 8);
        float4 s1 = *(const float4*)(selfp + (size_t)n * DO + chunk * 8 + 4);
        v[0] = a[0] * invn + s0.x; v[1] = a[1] * invn + s0.y;
        v[2] = a[2] * invn + s0.z; v[3] = a[3] * invn + s0.w;
        v[4] = a[4] * invn + s1.x; v[5] = a[5] * invn + s1.y;
        v[6] = a[6] * invn + s1.z; v[7] = a[7] * invn + s1.w;
    } else {
#pragma unroll
        for (int j = 0; j < 8; j++) v[j] = 0.f;
    }
    float mv = -INFINITY;
    if (vc) {
#pragma unroll
        for (int j = 0; j < 8; j++) mv = fmaxf(mv, v[j]);
    }
#pragma unroll
    for (int off = 1; off <= 4; off <<= 1) mv = fmaxf(mv, __shfl_xor(mv, off, 8));
    float es = 0.f;
    if (vc) {
#pragma unroll
        for (int j = 0; j < 8; j++) es += expf(v[j] - mv);
    }
#pragma unroll
    for (int off = 1; off <= 4; off <<= 1) es += __shfl_xor(es, off, 8);
    if (vc) {
        float ls = mv + logf(es);
        float4 o0, o1;
        o0.x = v[0] - ls; o0.y = v[1] - ls; o0.z = v[2] - ls; o0.w = v[3] - ls;
        o1.x = v[4] - ls; o1.y = v[5] - ls; o1.z = v[6] - ls; o1.w = v[7] - ls;
        *(float4*)(out + (size_t)n * DO + chunk * 8) = o0;
        *(float4*)(out + (size_t)n * DO + chunk * 8 + 4) = o1;
    }
}

extern "C" void kernel_launch(void* const* d_in, const int* in_sizes, int n_in,
                              void* d_out, int out_size, void* d_ws, size_t ws_size,
                              hipStream_t stream) {
    const float* x   = (const float*)d_in[0];
    const int*  ei   = (const int*)d_in[1];
    const float* W1l = (const float*)d_in[2];
    const float* b1  = (const float*)d_in[3];
    const float* W1r = (const float*)d_in[4];
    const float* W2l = (const float*)d_in[5];
    const float* b2  = (const float*)d_in[6];
    const float* W2r = (const float*)d_in[7];
    float* out = (float*)d_out;

    const int E = in_sizes[1] / 2;
    const int N = NN;
    const int* src = ei;
    const int* dst = ei + E;
    const int nbe = (E + EPB - 1) / EPB;
    const int nsetup = ((N + 1) * 32 + TPB_S - 1) / TPB_S;

    size_t off = 0;
    auto alloc = [&](size_t nf) { size_t o = off; off += (nf + 63) & ~(size_t)63; return o; };
    size_t o_bcur   = alloc(NBUCK);                   // int (counts, memset to 0)
    size_t o_eb     = alloc((size_t)NBUCK * CAP);     // int
    size_t o_col    = alloc((size_t)NBUCK * CAPP);    // int (padded CSR col)
    size_t o_rowptr = alloc(N);                       // int
    size_t o_cnt    = alloc(N);                       // int
    size_t o_inv    = alloc(N);                       // f32
    size_t o_xb     = alloc((size_t)(N + 1) * 32);    // u32 (64 bf16/row, +dummy)
    size_t o_p2     = alloc((size_t)(N + 1) * 10);    // u32 (40 fp8/row, +dummy) = 4MB
    size_t o_selfp  = alloc((size_t)N * DO);          // f32
    size_t o_wb1    = alloc(16384 / 2);
    size_t o_wb2    = alloc(10240 / 2);
    (void)ws_size;

    float* ws = (float*)d_ws;
    int* bcur   = (int*)(ws + o_bcur);
    int* eb     = (int*)(ws + o_eb);
    int* col    = (int*)(ws + o_col);
    int* rowptr = (int*)(ws + o_rowptr);
    int* cnt    = (int*)(ws + o_cnt);
    float* inv  = ws + o_inv;
    unsigned* xb = (unsigned*)(ws + o_xb);
    unsigned* p2 = (unsigned*)(ws + o_p2);
    float* selfp = ws + o_selfp;
    unsigned short* WB1 = (unsigned short*)(ws + o_wb1);
    unsigned short* WB2 = (unsigned short*)(ws + o_wb2);

    hipMemsetAsync(bcur, 0, NBUCK * sizeof(int), stream);

    setup_scatter_kernel<<<nbe + nsetup, TPB_S, 0, stream>>>(
        x, W1l, W1r, W2l, W2r, xb, WB1, WB2, p2, src, dst, bcur, eb, nbe, E, N);

    bucket_fill_kernel<<<NBUCK, 256, 0, stream>>>(eb, bcur, rowptr, cnt, inv, col, N);

    agg_gemm12_kernel<<<(N + 63) / 64, 256, 0, stream>>>(
        xb, rowptr, cnt, inv, col, WB1, b1, WB2, b2, p2, selfp, N);

    agg2_softmax_kernel<<<(N * 8 + 255) / 256, 256, 0, stream>>>(p2, selfp, rowptr, cnt, inv, col, out, N);
}

// Round 5
// 199.654 us; speedup vs baseline: 1.0220x; 1.0220x over previous
//
#include <hip/hip_runtime.h>
#include <math.h>

#define NN 100000
#define DI 64
#define DH 128
#define DO 40

#define NBUCK 512
#define NPB 196          // nodes per bucket: 512*196 = 100352 >= 100000
#define CAP 3712         // bucket capacity: mean 3125 + ~10.5 sigma
#define CAPP 5120        // padded col capacity: CAP + NPB*7 = 5084, rounded to 64
#define EPB 4096         // edges per scatter block
#define TPB_S 512        // threads per scatter/setup block
#define KE (EPB / TPB_S) // edges per thread = 8

typedef __attribute__((ext_vector_type(8))) short bf16x8;
typedef __attribute__((ext_vector_type(4))) float f32x4;
typedef __attribute__((ext_vector_type(2))) float f32x2;

__device__ __forceinline__ unsigned short bf16r(float a) {
    unsigned u = __float_as_uint(a);
    u = (u + 0x7FFF + ((u >> 16) & 1)) >> 16;
    return (unsigned short)u;
}
__device__ __forceinline__ unsigned bf16pair(float a, float b) {
    return (unsigned)bf16r(a) | ((unsigned)bf16r(b) << 16);
}
__device__ __forceinline__ float bflo(unsigned u) { return __uint_as_float(u << 16); }
__device__ __forceinline__ float bfhi(unsigned u) { return __uint_as_float(u & 0xFFFF0000u); }

// ---------- fused: scatter blocks [0,nbe) + setup blocks [nbe, nbe+nsetup) ----------
__global__ __launch_bounds__(TPB_S) void setup_scatter_kernel(
        const float* __restrict__ x, const float* __restrict__ W1l,
        const float* __restrict__ W1r, const float* __restrict__ W2l,
        const float* __restrict__ W2r,
        unsigned* __restrict__ xb, unsigned short* __restrict__ WB1,
        unsigned short* __restrict__ WB2, unsigned* __restrict__ p2,
        const int* __restrict__ src, const int* __restrict__ dst,
        int* __restrict__ bcur, int* __restrict__ eb,
        int nbe, int E, int N) {
    __shared__ int h[NBUCK];
    int t = threadIdx.x;
    if ((int)blockIdx.x < nbe) {
        // ---- bucket scatter: eb[pos] = (local<<17)|src ----
        if (t < NBUCK) h[t] = 0;
        __syncthreads();
        int base = blockIdx.x * EPB;
        int end = base + EPB; if (end > E) end = E;
        int dloc[KE];
#pragma unroll
        for (int k = 0; k < KE; k++) {
            int i = base + t + k * TPB_S;
            dloc[k] = (i < end) ? dst[i] : -1;
        }
#pragma unroll
        for (int k = 0; k < KE; k++)
            if (dloc[k] >= 0) atomicAdd(&h[(unsigned)dloc[k] / NPB], 1);
        __syncthreads();
        if (t < NBUCK) {
            int v = h[t];
            h[t] = v ? (atomicAdd(&bcur[t], v) + t * CAP) : 0;
        }
        __syncthreads();
#pragma unroll
        for (int k = 0; k < KE; k++) {
            int d = dloc[k];
            if (d >= 0) {
                unsigned bk = (unsigned)d / NPB;
                int local = d - (int)bk * NPB;
                int pos = atomicAdd(&h[bk], 1);
                eb[pos] = (local << 17) | src[base + t + k * TPB_S];
            }
        }
    } else {
        // ---- setup: x->bf16, weight packs, p2 dummy row ----
        int idx = (blockIdx.x - nbe) * TPB_S + t;
        if (idx < (N + 1) * 32) {
            if (idx < N * 32) {
                float2 f = ((const float2*)x)[idx];
                xb[idx] = bf16pair(f.x, f.y);
            } else {
                xb[idx] = 0;          // dummy row N of xb
            }
        }
        if (idx < 16384) {
            int j = idx & 7, lane = (idx >> 3) & 63, ks = (idx >> 9) & 3, nt = idx >> 11;
            int k = ks * 32 + (lane >> 4) * 8 + j;
            int n = nt * 16 + (lane & 15);
            float v = (k < DI) ? W1l[n * DI + k] : W1r[n * DI + (k - DI)];
            WB1[idx] = bf16r(v);
        }
        if (idx >= 16384 && idx < 16384 + 10240) {
            int idx2 = idx - 16384;
            int j = idx2 & 7, lane = (idx2 >> 3) & 63, ks = (idx2 >> 9) & 3, nt = idx2 >> 11;
            int k = ks * 32 + (lane >> 4) * 8 + j;
            int n = nt * 16 + (lane & 15);
            float v = (n < DO) ? W2l[n * DH + k] : W2r[(n - DO) * DH + k];
            WB2[idx2] = bf16r(v);
        }
        if (idx < 10) p2[(size_t)N * 10 + idx] = 0;   // dummy fp8 row N (decodes to 0)
    }
}

// ---------- fill: per bucket -> rowptr/cnt/inv + col padded to x8 with dummy NN ----------
__global__ __launch_bounds__(256) void bucket_fill_kernel(const int* __restrict__ eb,
                                                          const int* __restrict__ bend,
                                                          int* __restrict__ rowptr,
                                                          int* __restrict__ cntg,
                                                          float* __restrict__ inv,
                                                          int* __restrict__ col, int N) {
    __shared__ int scnt[256];
    __shared__ int scur[256];
    __shared__ int sbase[256];
    int b = blockIdx.x, t = threadIdx.x;
    int ebeg = b * CAP, eend = ebeg + bend[b];   // bend holds counts
    scnt[t] = 0;
    __syncthreads();
    for (int i = ebeg + t; i < eend; i += 256)
        atomicAdd(&scnt[eb[i] >> 17], 1);
    __syncthreads();
    int myc = scnt[t];
    int pc = (myc + 7) & ~7;                      // pad to x8 for 8-wide gathers
    scnt[t] = pc;
    __syncthreads();
    for (int off = 1; off < 256; off <<= 1) {
        int tmp = (t >= off) ? scnt[t - off] : 0;
        __syncthreads();
        scnt[t] += tmp;
        __syncthreads();
    }
    int excl = scnt[t] - pc;
    int base = b * CAPP + excl;
    int node = b * NPB + t;
    if (t < NPB && node < N) {
        rowptr[node] = base;
        cntg[node] = myc;
        inv[node] = 1.0f / (float)(myc > 0 ? myc : 1);
    }
    scur[t] = base;
    sbase[t] = base;
    __syncthreads();
    for (int i = ebeg + t; i < eend; i += 256) {
        int pk = eb[i];
        int pos = atomicAdd(&scur[pk >> 17], 1);
        col[pos] = pk & 0x1FFFF;
    }
    __syncthreads();
    if (t < NPB) {
        int bs = sbase[t];
        for (int i = myc; i < pc; i++) col[bs + i] = NN;
    }
}

// ---------- fused agg1 + GEMM1 + GEMM2: BARRIER-FREE, wave-private rows ----------
// Phase A: 8 lanes/node, 4-wide uint4 gather, DUAL independent node chains per
//          lane (rows g and g+8) -> 128B in flight/lane, two addr->gather chains.
// Phase B: GEMM1 h=relu(A@Wcat1+b1), in place.
// Phase C: GEMM2 -> p2 (fp8, staged via float alias of own sh rows) + selfp.
__global__ __launch_bounds__(256) void agg_gemm12_kernel(
        const unsigned* __restrict__ xb, const int* __restrict__ rowptr,
        const int* __restrict__ cnt, const float* __restrict__ inv,
        const int* __restrict__ col,
        const unsigned short* __restrict__ WB1, const float* __restrict__ b1,
        const unsigned short* __restrict__ WB2, const float* __restrict__ b2,
        unsigned* __restrict__ p2, float* __restrict__ selfp, int N) {
    __shared__ unsigned short sh[64][136];   // A-tile -> h-tile -> f32 stage (aliased)
    int t = threadIdx.x;
    int w = t >> 6, lane = t & 63;
    int lw = w * 16;
    int g8 = (t >> 3) & 7;                   // gather group within wave: 0..7
    int chunk = t & 7;                       // 16B chunk within row
    int rbase = blockIdx.x * 64 + lw;

    // ---- Phase A: dual-chain aggregate of rows lw+g8 and lw+g8+8 ----
    {
        int lrA = lw + g8, lrB = lw + g8 + 8;
        int nA = blockIdx.x * 64 + lrA;
        int nB = blockIdx.x * 64 + lrB;
        bool vA = (nA < N), vB = (nB < N);
        int begA = 0, degpA = 0, begB = 0, degpB = 0;
        float invA = 0.f, invB = 0.f;
        if (vA) { begA = rowptr[nA]; degpA = (cnt[nA] + 3) & ~3; invA = inv[nA]; }
        if (vB) { begB = rowptr[nB]; degpB = (cnt[nB] + 3) & ~3; invB = inv[nB]; }
        float aA[8], aB[8];
#pragma unroll
        for (int j = 0; j < 8; j++) { aA[j] = 0.f; aB[j] = 0.f; }
        int degm = degpA > degpB ? degpA : degpB;
        for (int i = 0; i < degm; i += 4) {
            // unconditional col loads (array has +64 int slack); select dummy after
            int4 cA = *(const int4*)(col + begA + i);
            int4 cB = *(const int4*)(col + begB + i);
            bool okA = (i < degpA), okB = (i < degpB);
            int a0 = okA ? cA.x : NN, a1 = okA ? cA.y : NN;
            int a2 = okA ? cA.z : NN, a3 = okA ? cA.w : NN;
            int b0 = okB ? cB.x : NN, b1_ = okB ? cB.y : NN;
            int b2_ = okB ? cB.z : NN, b3 = okB ? cB.w : NN;
            uint4 uA0 = *(const uint4*)(xb + (size_t)a0 * 32 + chunk * 4);
            uint4 uA1 = *(const uint4*)(xb + (size_t)a1 * 32 + chunk * 4);
            uint4 uA2 = *(const uint4*)(xb + (size_t)a2 * 32 + chunk * 4);
            uint4 uA3 = *(const uint4*)(xb + (size_t)a3 * 32 + chunk * 4);
            uint4 uB0 = *(const uint4*)(xb + (size_t)b0 * 32 + chunk * 4);
            uint4 uB1 = *(const uint4*)(xb + (size_t)b1_ * 32 + chunk * 4);
            uint4 uB2 = *(const uint4*)(xb + (size_t)b2_ * 32 + chunk * 4);
            uint4 uB3 = *(const uint4*)(xb + (size_t)b3 * 32 + chunk * 4);
            aA[0] += bflo(uA0.x) + bflo(uA1.x) + bflo(uA2.x) + bflo(uA3.x);
            aA[1] += bfhi(uA0.x) + bfhi(uA1.x) + bfhi(uA2.x) + bfhi(uA3.x);
            aA[2] += bflo(uA0.y) + bflo(uA1.y) + bflo(uA2.y) + bflo(uA3.y);
            aA[3] += bfhi(uA0.y) + bfhi(uA1.y) + bfhi(uA2.y) + bfhi(uA3.y);
            aA[4] += bflo(uA0.z) + bflo(uA1.z) + bflo(uA2.z) + bflo(uA3.z);
            aA[5] += bfhi(uA0.z) + bfhi(uA1.z) + bfhi(uA2.z) + bfhi(uA3.z);
            aA[6] += bflo(uA0.w) + bflo(uA1.w) + bflo(uA2.w) + bflo(uA3.w);
            aA[7] += bfhi(uA0.w) + bfhi(uA1.w) + bfhi(uA2.w) + bfhi(uA3.w);
            aB[0] += bflo(uB0.x) + bflo(uB1.x) + bflo(uB2.x) + bflo(uB3.x);
            aB[1] += bfhi(uB0.x) + bfhi(uB1.x) + bfhi(uB2.x) + bfhi(uB3.x);
            aB[2] += bflo(uB0.y) + bflo(uB1.y) + bflo(uB2.y) + bflo(uB3.y);
            aB[3] += bfhi(uB0.y) + bfhi(uB1.y) + bfhi(uB2.y) + bfhi(uB3.y);
            aB[4] += bflo(uB0.z) + bflo(uB1.z) + bflo(uB2.z) + bflo(uB3.z);
            aB[5] += bfhi(uB0.z) + bfhi(uB1.z) + bfhi(uB2.z) + bfhi(uB3.z);
            aB[6] += bflo(uB0.w) + bflo(uB1.w) + bflo(uB2.w) + bflo(uB3.w);
            aB[7] += bfhi(uB0.w) + bfhi(uB1.w) + bfhi(uB2.w) + bfhi(uB3.w);
        }
        uint4 suA = make_uint4(0, 0, 0, 0), suB = make_uint4(0, 0, 0, 0);
        if (vA) suA = *(const uint4*)(xb + (size_t)nA * 32 + chunk * 4);
        if (vB) suB = *(const uint4*)(xb + (size_t)nB * 32 + chunk * 4);
        uint4 oA, oB;
        oA.x = bf16pair(aA[0] * invA, aA[1] * invA);
        oA.y = bf16pair(aA[2] * invA, aA[3] * invA);
        oA.z = bf16pair(aA[4] * invA, aA[5] * invA);
        oA.w = bf16pair(aA[6] * invA, aA[7] * invA);
        oB.x = bf16pair(aB[0] * invB, aB[1] * invB);
        oB.y = bf16pair(aB[2] * invB, aB[3] * invB);
        oB.z = bf16pair(aB[4] * invB, aB[5] * invB);
        oB.w = bf16pair(aB[6] * invB, aB[7] * invB);
        *(uint4*)&sh[lrA][chunk * 8] = oA;
        *(uint4*)&sh[lrA][64 + chunk * 8] = suA;
        *(uint4*)&sh[lrB][chunk * 8] = oB;
        *(uint4*)&sh[lrB][64 + chunk * 8] = suB;
    }
    asm volatile("" ::: "memory");

    // ---- Phase B: GEMM1 (reads/writes only own rows) ----
    int quad = lane >> 4, m = lane & 15;
    f32x4 acc[8];
#pragma unroll
    for (int nt = 0; nt < 8; nt++) acc[nt] = (f32x4)(0.f);
#pragma unroll
    for (int ks = 0; ks < 4; ks++) {
        bf16x8 a = *(const bf16x8*)(&sh[lw + m][ks * 32 + quad * 8]);
#pragma unroll
        for (int nt = 0; nt < 8; nt++) {
            bf16x8 b = *(const bf16x8*)(WB1 + ((size_t)(nt * 4 + ks) * 64 + lane) * 8);
            acc[nt] = __builtin_amdgcn_mfma_f32_16x16x32_bf16(a, b, acc[nt], 0, 0, 0);
        }
    }
    asm volatile("" ::: "memory");
#pragma unroll
    for (int nt = 0; nt < 8; nt++) {
        int colj = nt * 16 + m;
        float bj = b1[colj];
#pragma unroll
        for (int r = 0; r < 4; r++) {
            sh[lw + quad * 4 + r][colj] = bf16r(fmaxf(acc[nt][r] + bj, 0.f));
        }
    }
    asm volatile("" ::: "memory");

    // ---- Phase C: GEMM2 ----
    f32x4 acc2[5];
#pragma unroll
    for (int nt = 0; nt < 5; nt++) acc2[nt] = (f32x4)(0.f);
#pragma unroll
    for (int ks = 0; ks < 4; ks++) {
        bf16x8 a = *(const bf16x8*)(&sh[lw + m][ks * 32 + quad * 8]);
#pragma unroll
        for (int nt = 0; nt < 5; nt++) {
            bf16x8 b = *(const bf16x8*)(WB2 + ((size_t)(nt * 4 + ks) * 64 + lane) * 8);
            acc2[nt] = __builtin_amdgcn_mfma_f32_16x16x32_bf16(a, b, acc2[nt], 0, 0, 0);
        }
    }
    asm volatile("" ::: "memory");
    float* stw = (float*)&sh[lw][0];         // 16 rows x 41 f32 = 2624 B <= 4352 B
#pragma unroll
    for (int nt = 0; nt < 5; nt++) {
        int colj = nt * 16 + m;
#pragma unroll
        for (int r = 0; r < 4; r++) {
            int row = rbase + quad * 4 + r;
            float v = acc2[nt][r];
            if (colj < 40) {
                stw[(quad * 4 + r) * 41 + colj] = v;
            } else if (row < N) {
                selfp[(size_t)row * 40 + (colj - 40)] = v + b2[colj - 40];
            }
        }
    }
    asm volatile("" ::: "memory");
    for (int i = lane; i < 160; i += 64) {
        int lr = i / 10, dw = i - lr * 10;
        int grow = rbase + lr;
        if (grow < N) {
            float v0 = stw[lr * 41 + dw * 4 + 0], v1 = stw[lr * 41 + dw * 4 + 1];
            float v2 = stw[lr * 41 + dw * 4 + 2], v3 = stw[lr * 41 + dw * 4 + 3];
            unsigned u = __builtin_amdgcn_cvt_pk_fp8_f32(v0, v1, 0u, false);
            u = __builtin_amdgcn_cvt_pk_fp8_f32(v2, v3, u, true);
            p2[(size_t)grow * 10 + dw] = u;
        }
    }
}

// ---------- agg2 + log_softmax: 8 lanes/node (5 active), edges 8-wide ----------
__global__ void agg2_softmax_kernel(const unsigned* __restrict__ p2,
                                    const float* __restrict__ selfp,
                                    const int* __restrict__ rowptr,
                                    const int* __restrict__ cnt,
                                    const float* __restrict__ inv,
                                    const int* __restrict__ col,
                                    float* __restrict__ out, int N) {
    int n = (blockIdx.x * 256 + threadIdx.x) >> 3;
    int chunk = threadIdx.x & 7;
    if (n >= N) return;
    int beg = rowptr[n], deg = cnt[n];
    int degp = (deg + 7) & ~7;
    bool vc = (chunk < 5);
    float a[8];
#pragma unroll
    for (int j = 0; j < 8; j++) a[j] = 0.f;
    for (int i = 0; i < degp; i += 8) {
        int ss[8];
#pragma unroll
        for (int k = 0; k < 8; k++) ss[k] = col[beg + i + k];
        if (vc) {
            uint2 uu[8];
#pragma unroll
            for (int k = 0; k < 8; k++)
                uu[k] = *(const uint2*)(p2 + (size_t)ss[k] * 10 + chunk * 2);
#pragma unroll
            for (int k = 0; k < 8; k++) {
                f32x2 d;
                d = __builtin_amdgcn_cvt_pk_f32_fp8(uu[k].x, false); a[0] += d.x; a[1] += d.y;
                d = __builtin_amdgcn_cvt_pk_f32_fp8(uu[k].x, true);  a[2] += d.x; a[3] += d.y;
                d = __builtin_amdgcn_cvt_pk_f32_fp8(uu[k].y, false); a[4] += d.x; a[5] += d.y;
                d = __builtin_amdgcn_cvt_pk_f32_fp8(uu[k].y, true);  a[6] += d.x; a[7] += d.y;
            }
        }
    }
    float invn = inv[n];
    float v[8];
    if (vc) {
        float4 s0 = *(const float4*)(selfp + (size_t)n * DO + chunk * 8);
        float4 s1 = *(const float4*)(selfp + (size_t)n * DO + chunk * 8 + 4);
        v[0] = a[0] * invn + s0.x; v[1] = a[1] * invn + s0.y;
        v[2] = a[2] * invn + s0.z; v[3] = a[3] * invn + s0.w;
        v[4] = a[4] * invn + s1.x; v[5] = a[5] * invn + s1.y;
        v[6] = a[6] * invn + s1.z; v[7] = a[7] * invn + s1.w;
    } else {
#pragma unroll
        for (int j = 0; j < 8; j++) v[j] = 0.f;
    }
    float mv = -INFINITY;
    if (vc) {
#pragma unroll
        for (int j = 0; j < 8; j++) mv = fmaxf(mv, v[j]);
    }
#pragma unroll
    for (int off = 1; off <= 4; off <<= 1) mv = fmaxf(mv, __shfl_xor(mv, off, 8));
    float es = 0.f;
    if (vc) {
#pragma unroll
        for (int j = 0; j < 8; j++) es += expf(v[j] - mv);
    }
#pragma unroll
    for (int off = 1; off <= 4; off <<= 1) es += __shfl_xor(es, off, 8);
    if (vc) {
        float ls = mv + logf(es);
        float4 o0, o1;
        o0.x = v[0] - ls; o0.y = v[1] - ls; o0.z = v[2] - ls; o0.w = v[3] - ls;
        o1.x = v[4] - ls; o1.y = v[5] - ls; o1.z = v[6] - ls; o1.w = v[7] - ls;
        *(float4*)(out + (size_t)n * DO + chunk * 8) = o0;
        *(float4*)(out + (size_t)n * DO + chunk * 8 + 4) = o1;
    }
}

extern "C" void kernel_launch(void* const* d_in, const int* in_sizes, int n_in,
                              void* d_out, int out_size, void* d_ws, size_t ws_size,
                              hipStream_t stream) {
    const float* x   = (const float*)d_in[0];
    const int*  ei   = (const int*)d_in[1];
    const float* W1l = (const float*)d_in[2];
    const float* b1  = (const float*)d_in[3];
    const float* W1r = (const float*)d_in[4];
    const float* W2l = (const float*)d_in[5];
    const float* b2  = (const float*)d_in[6];
    const float* W2r = (const float*)d_in[7];
    float* out = (float*)d_out;

    const int E = in_sizes[1] / 2;
    const int N = NN;
    const int* src = ei;
    const int* dst = ei + E;
    const int nbe = (E + EPB - 1) / EPB;
    const int nsetup = ((N + 1) * 32 + TPB_S - 1) / TPB_S;

    size_t off = 0;
    auto alloc = [&](size_t nf) { size_t o = off; off += (nf + 63) & ~(size_t)63; return o; };
    size_t o_bcur   = alloc(NBUCK);                   // int (counts, memset to 0)
    size_t o_eb     = alloc((size_t)NBUCK * CAP);     // int
    size_t o_col    = alloc((size_t)NBUCK * CAPP + 64); // int (padded CSR col + slack)
    size_t o_rowptr = alloc(N);                       // int
    size_t o_cnt    = alloc(N);                       // int
    size_t o_inv    = alloc(N);                       // f32
    size_t o_xb     = alloc((size_t)(N + 1) * 32);    // u32 (64 bf16/row, +dummy)
    size_t o_p2     = alloc((size_t)(N + 1) * 10);    // u32 (40 fp8/row, +dummy) = 4MB
    size_t o_selfp  = alloc((size_t)N * DO);          // f32
    size_t o_wb1    = alloc(16384 / 2);
    size_t o_wb2    = alloc(10240 / 2);
    (void)ws_size;

    float* ws = (float*)d_ws;
    int* bcur   = (int*)(ws + o_bcur);
    int* eb     = (int*)(ws + o_eb);
    int* col    = (int*)(ws + o_col);
    int* rowptr = (int*)(ws + o_rowptr);
    int* cnt    = (int*)(ws + o_cnt);
    float* inv  = ws + o_inv;
    unsigned* xb = (unsigned*)(ws + o_xb);
    unsigned* p2 = (unsigned*)(ws + o_p2);
    float* selfp = ws + o_selfp;
    unsigned short* WB1 = (unsigned short*)(ws + o_wb1);
    unsigned short* WB2 = (unsigned short*)(ws + o_wb2);

    hipMemsetAsync(bcur, 0, NBUCK * sizeof(int), stream);

    setup_scatter_kernel<<<nbe + nsetup, TPB_S, 0, stream>>>(
        x, W1l, W1r, W2l, W2r, xb, WB1, WB2, p2, src, dst, bcur, eb, nbe, E, N);

    bucket_fill_kernel<<<NBUCK, 256, 0, stream>>>(eb, bcur, rowptr, cnt, inv, col, N);

    agg_gemm12_kernel<<<(N + 63) / 64, 256, 0, stream>>>(
        xb, rowptr, cnt, inv, col, WB1, b1, WB2, b2, p2, selfp, N);

    agg2_softmax_kernel<<<(N * 8 + 255) / 256, 256, 0, stream>>>(p2, selfp, rowptr, cnt, inv, col, out, N);
}

// Round 6
// 196.371 us; speedup vs baseline: 1.0391x; 1.0167x over previous
//
#include <hip/hip_runtime.h>
#include <math.h>

#define NN 100000
#define DI 64
#define DH 128
#define DO 40

#define NBUCK 512
#define NPB 196          // nodes per bucket: 512*196 = 100352 >= 100000
#define CAP 3712         // bucket capacity: mean 3125 + ~10.5 sigma
#define CAPP 5120        // padded col capacity: CAP + NPB*7 = 5084, rounded to 64
#define EPB 4096         // edges per scatter block
#define TPB_S 512        // threads per scatter/setup block
#define KE (EPB / TPB_S) // edges per thread = 8

typedef __attribute__((ext_vector_type(8))) short bf16x8;
typedef __attribute__((ext_vector_type(4))) float f32x4;
typedef __attribute__((ext_vector_type(2))) float f32x2;

__device__ __forceinline__ unsigned short bf16r(float a) {
    unsigned u = __float_as_uint(a);
    u = (u + 0x7FFF + ((u >> 16) & 1)) >> 16;
    return (unsigned short)u;
}
__device__ __forceinline__ unsigned bf16pair(float a, float b) {
    return (unsigned)bf16r(a) | ((unsigned)bf16r(b) << 16);
}
__device__ __forceinline__ float bflo(unsigned u) { return __uint_as_float(u << 16); }
__device__ __forceinline__ float bfhi(unsigned u) { return __uint_as_float(u & 0xFFFF0000u); }

// ---------- fused: scatter blocks [0,nbe) + setup blocks [nbe, nbe+nsetup) ----------
__global__ __launch_bounds__(TPB_S) void setup_scatter_kernel(
        const float* __restrict__ x, const float* __restrict__ W1l,
        const float* __restrict__ W1r, const float* __restrict__ W2l,
        const float* __restrict__ W2r,
        unsigned* __restrict__ xb, unsigned short* __restrict__ WB1,
        unsigned short* __restrict__ WB2, unsigned* __restrict__ p2,
        const int* __restrict__ src, const int* __restrict__ dst,
        int* __restrict__ bcur, int* __restrict__ eb,
        int nbe, int E, int N) {
    __shared__ int h[NBUCK];
    int t = threadIdx.x;
    if ((int)blockIdx.x < nbe) {
        // ---- bucket scatter: eb[pos] = (local<<17)|src ----
        if (t < NBUCK) h[t] = 0;
        __syncthreads();
        int base = blockIdx.x * EPB;
        int end = base + EPB; if (end > E) end = E;
        int dloc[KE];
#pragma unroll
        for (int k = 0; k < KE; k++) {
            int i = base + t + k * TPB_S;
            dloc[k] = (i < end) ? dst[i] : -1;
        }
#pragma unroll
        for (int k = 0; k < KE; k++)
            if (dloc[k] >= 0) atomicAdd(&h[(unsigned)dloc[k] / NPB], 1);
        __syncthreads();
        if (t < NBUCK) {
            int v = h[t];
            h[t] = v ? (atomicAdd(&bcur[t], v) + t * CAP) : 0;
        }
        __syncthreads();
#pragma unroll
        for (int k = 0; k < KE; k++) {
            int d = dloc[k];
            if (d >= 0) {
                unsigned bk = (unsigned)d / NPB;
                int local = d - (int)bk * NPB;
                int pos = atomicAdd(&h[bk], 1);
                eb[pos] = (local << 17) | src[base + t + k * TPB_S];
            }
        }
    } else {
        // ---- setup: x->bf16, weight packs, p2 dummy row ----
        int idx = (blockIdx.x - nbe) * TPB_S + t;
        if (idx < (N + 1) * 32) {
            if (idx < N * 32) {
                float2 f = ((const float2*)x)[idx];
                xb[idx] = bf16pair(f.x, f.y);
            } else {
                xb[idx] = 0;          // dummy row N of xb
            }
        }
        if (idx < 16384) {
            int j = idx & 7, lane = (idx >> 3) & 63, ks = (idx >> 9) & 3, nt = idx >> 11;
            int k = ks * 32 + (lane >> 4) * 8 + j;
            int n = nt * 16 + (lane & 15);
            float v = (k < DI) ? W1l[n * DI + k] : W1r[n * DI + (k - DI)];
            WB1[idx] = bf16r(v);
        }
        if (idx >= 16384 && idx < 16384 + 10240) {
            int idx2 = idx - 16384;
            int j = idx2 & 7, lane = (idx2 >> 3) & 63, ks = (idx2 >> 9) & 3, nt = idx2 >> 11;
            int k = ks * 32 + (lane >> 4) * 8 + j;
            int n = nt * 16 + (lane & 15);
            float v = (n < DO) ? W2l[n * DH + k] : W2r[(n - DO) * DH + k];
            WB2[idx2] = bf16r(v);
        }
        if (idx < 10) p2[(size_t)N * 10 + idx] = 0;   // dummy fp8 row N (decodes to 0)
    }
}

// ---------- fill: per bucket -> rowptr/cnt/inv + col padded to x8 with dummy NN ----------
__global__ __launch_bounds__(256) void bucket_fill_kernel(const int* __restrict__ eb,
                                                          const int* __restrict__ bend,
                                                          int* __restrict__ rowptr,
                                                          int* __restrict__ cntg,
                                                          float* __restrict__ inv,
                                                          int* __restrict__ col, int N) {
    __shared__ int scnt[256];
    __shared__ int scur[256];
    __shared__ int sbase[256];
    int b = blockIdx.x, t = threadIdx.x;
    int ebeg = b * CAP, eend = ebeg + bend[b];   // bend holds counts
    scnt[t] = 0;
    __syncthreads();
    for (int i = ebeg + t; i < eend; i += 256)
        atomicAdd(&scnt[eb[i] >> 17], 1);
    __syncthreads();
    int myc = scnt[t];
    int pc = (myc + 7) & ~7;                      // pad to x8 for 8-wide gathers
    scnt[t] = pc;
    __syncthreads();
    for (int off = 1; off < 256; off <<= 1) {
        int tmp = (t >= off) ? scnt[t - off] : 0;
        __syncthreads();
        scnt[t] += tmp;
        __syncthreads();
    }
    int excl = scnt[t] - pc;
    int base = b * CAPP + excl;
    int node = b * NPB + t;
    if (t < NPB && node < N) {
        rowptr[node] = base;
        cntg[node] = myc;
        inv[node] = 1.0f / (float)(myc > 0 ? myc : 1);
    }
    scur[t] = base;
    sbase[t] = base;
    __syncthreads();
    for (int i = ebeg + t; i < eend; i += 256) {
        int pk = eb[i];
        int pos = atomicAdd(&scur[pk >> 17], 1);
        col[pos] = pk & 0x1FFFF;
    }
    __syncthreads();
    if (t < NPB) {
        int bs = sbase[t];
        for (int i = myc; i < pc; i++) col[bs + i] = NN;
    }
}

// ---------- fused agg1 + GEMM1 + GEMM2: BARRIER-FREE, wave-private rows ----------
// Phase A: 8 lanes/node, 4-wide uint4 gather, col quad PREFETCHED one iter ahead
//          so the steady-state critical path is gather latency only.
// Phase B: GEMM1 h=relu(A@Wcat1+b1), in place.
// Phase C: GEMM2 -> p2 (fp8, staged via float alias of own sh rows) + selfp.
__global__ __launch_bounds__(256) void agg_gemm12_kernel(
        const unsigned* __restrict__ xb, const int* __restrict__ rowptr,
        const int* __restrict__ cnt, const float* __restrict__ inv,
        const int* __restrict__ col,
        const unsigned short* __restrict__ WB1, const float* __restrict__ b1,
        const unsigned short* __restrict__ WB2, const float* __restrict__ b2,
        unsigned* __restrict__ p2, float* __restrict__ selfp, int N) {
    __shared__ unsigned short sh[64][136];   // A-tile -> h-tile -> f32 stage (aliased)
    int t = threadIdx.x;
    int w = t >> 6, lane = t & 63;
    int lw = w * 16;
    int g8 = (t >> 3) & 7;                   // gather group within wave: 0..7
    int chunk = t & 7;                       // 16B chunk within row
    int rbase = blockIdx.x * 64 + lw;

    // ---- Phase A: aggregate wave-private rows (2 passes x 8 nodes) ----
#pragma unroll
    for (int it = 0; it < 2; ++it) {
        int lr = lw + g8 + it * 8;
        int n = blockIdx.x * 64 + lr;
        float a[8];
#pragma unroll
        for (int j = 0; j < 8; j++) a[j] = 0.f;
        float invn = 0.f;
        uint4 u = make_uint4(0, 0, 0, 0);
        if (n < N) {
            int beg = rowptr[n], deg = cnt[n];
            int degp = (deg + 3) & ~3;
            // prime: first col quad (col has +64-int slack; pads decode to row NN=0)
            int4 c = *(const int4*)(col + beg);
            for (int i = 0; i < degp; i += 4) {
                int4 cn = *(const int4*)(col + beg + i + 4);  // prefetch next quad
                uint4 u0 = *(const uint4*)(xb + (size_t)c.x * 32 + chunk * 4);
                uint4 u1 = *(const uint4*)(xb + (size_t)c.y * 32 + chunk * 4);
                uint4 u2 = *(const uint4*)(xb + (size_t)c.z * 32 + chunk * 4);
                uint4 u3 = *(const uint4*)(xb + (size_t)c.w * 32 + chunk * 4);
                a[0] += bflo(u0.x) + bflo(u1.x) + bflo(u2.x) + bflo(u3.x);
                a[1] += bfhi(u0.x) + bfhi(u1.x) + bfhi(u2.x) + bfhi(u3.x);
                a[2] += bflo(u0.y) + bflo(u1.y) + bflo(u2.y) + bflo(u3.y);
                a[3] += bfhi(u0.y) + bfhi(u1.y) + bfhi(u2.y) + bfhi(u3.y);
                a[4] += bflo(u0.z) + bflo(u1.z) + bflo(u2.z) + bflo(u3.z);
                a[5] += bfhi(u0.z) + bfhi(u1.z) + bfhi(u2.z) + bfhi(u3.z);
                a[6] += bflo(u0.w) + bflo(u1.w) + bflo(u2.w) + bflo(u3.w);
                a[7] += bfhi(u0.w) + bfhi(u1.w) + bfhi(u2.w) + bfhi(u3.w);
                c = cn;
            }
            invn = inv[n];
            u = *(const uint4*)(xb + (size_t)n * 32 + chunk * 4);
        }
        uint4 o;
        o.x = bf16pair(a[0] * invn, a[1] * invn);
        o.y = bf16pair(a[2] * invn, a[3] * invn);
        o.z = bf16pair(a[4] * invn, a[5] * invn);
        o.w = bf16pair(a[6] * invn, a[7] * invn);
        *(uint4*)&sh[lr][chunk * 8] = o;        // agg half (cols 0..63)
        *(uint4*)&sh[lr][64 + chunk * 8] = u;   // self half (cols 64..127)
    }
    asm volatile("" ::: "memory");

    // ---- Phase B: GEMM1 (reads/writes only own rows) ----
    int quad = lane >> 4, m = lane & 15;
    f32x4 acc[8];
#pragma unroll
    for (int nt = 0; nt < 8; nt++) acc[nt] = (f32x4)(0.f);
#pragma unroll
    for (int ks = 0; ks < 4; ks++) {
        bf16x8 a = *(const bf16x8*)(&sh[lw + m][ks * 32 + quad * 8]);
#pragma unroll
        for (int nt = 0; nt < 8; nt++) {
            bf16x8 b = *(const bf16x8*)(WB1 + ((size_t)(nt * 4 + ks) * 64 + lane) * 8);
            acc[nt] = __builtin_amdgcn_mfma_f32_16x16x32_bf16(a, b, acc[nt], 0, 0, 0);
        }
    }
    asm volatile("" ::: "memory");
#pragma unroll
    for (int nt = 0; nt < 8; nt++) {
        int colj = nt * 16 + m;
        float bj = b1[colj];
#pragma unroll
        for (int r = 0; r < 4; r++) {
            sh[lw + quad * 4 + r][colj] = bf16r(fmaxf(acc[nt][r] + bj, 0.f));
        }
    }
    asm volatile("" ::: "memory");

    // ---- Phase C: GEMM2 ----
    f32x4 acc2[5];
#pragma unroll
    for (int nt = 0; nt < 5; nt++) acc2[nt] = (f32x4)(0.f);
#pragma unroll
    for (int ks = 0; ks < 4; ks++) {
        bf16x8 a = *(const bf16x8*)(&sh[lw + m][ks * 32 + quad * 8]);
#pragma unroll
        for (int nt = 0; nt < 5; nt++) {
            bf16x8 b = *(const bf16x8*)(WB2 + ((size_t)(nt * 4 + ks) * 64 + lane) * 8);
            acc2[nt] = __builtin_amdgcn_mfma_f32_16x16x32_bf16(a, b, acc2[nt], 0, 0, 0);
        }
    }
    asm volatile("" ::: "memory");
    float* stw = (float*)&sh[lw][0];         // 16 rows x 41 f32 = 2624 B <= 4352 B
#pragma unroll
    for (int nt = 0; nt < 5; nt++) {
        int colj = nt * 16 + m;
#pragma unroll
        for (int r = 0; r < 4; r++) {
            int row = rbase + quad * 4 + r;
            float v = acc2[nt][r];
            if (colj < 40) {
                stw[(quad * 4 + r) * 41 + colj] = v;
            } else if (row < N) {
                selfp[(size_t)row * 40 + (colj - 40)] = v + b2[colj - 40];
            }
        }
    }
    asm volatile("" ::: "memory");
    for (int i = lane; i < 160; i += 64) {
        int lr = i / 10, dw = i - lr * 10;
        int grow = rbase + lr;
        if (grow < N) {
            float v0 = stw[lr * 41 + dw * 4 + 0], v1 = stw[lr * 41 + dw * 4 + 1];
            float v2 = stw[lr * 41 + dw * 4 + 2], v3 = stw[lr * 41 + dw * 4 + 3];
            unsigned u = __builtin_amdgcn_cvt_pk_fp8_f32(v0, v1, 0u, false);
            u = __builtin_amdgcn_cvt_pk_fp8_f32(v2, v3, u, true);
            p2[(size_t)grow * 10 + dw] = u;
        }
    }
}

// ---------- agg2 + log_softmax: 8 lanes/node (5 active), edges 8-wide, col prefetch ----------
__global__ void agg2_softmax_kernel(const unsigned* __restrict__ p2,
                                    const float* __restrict__ selfp,
                                    const int* __restrict__ rowptr,
                                    const int* __restrict__ cnt,
                                    const float* __restrict__ inv,
                                    const int* __restrict__ col,
                                    float* __restrict__ out, int N) {
    int n = (blockIdx.x * 256 + threadIdx.x) >> 3;
    int chunk = threadIdx.x & 7;
    if (n >= N) return;
    int beg = rowptr[n], deg = cnt[n];
    int degp = (deg + 7) & ~7;
    bool vc = (chunk < 5);
    float a[8];
#pragma unroll
    for (int j = 0; j < 8; j++) a[j] = 0.f;
    // prime: first two col quads (col has +64-int slack; pads = row NN -> zeros)
    int4 c0 = *(const int4*)(col + beg);
    int4 c1 = *(const int4*)(col + beg + 4);
    for (int i = 0; i < degp; i += 8) {
        int4 n0 = *(const int4*)(col + beg + i + 8);   // prefetch next 8
        int4 n1 = *(const int4*)(col + beg + i + 12);
        int ss[8] = {c0.x, c0.y, c0.z, c0.w, c1.x, c1.y, c1.z, c1.w};
        if (vc) {
            uint2 uu[8];
#pragma unroll
            for (int k = 0; k < 8; k++)
                uu[k] = *(const uint2*)(p2 + (size_t)ss[k] * 10 + chunk * 2);
#pragma unroll
            for (int k = 0; k < 8; k++) {
                f32x2 d;
                d = __builtin_amdgcn_cvt_pk_f32_fp8(uu[k].x, false); a[0] += d.x; a[1] += d.y;
                d = __builtin_amdgcn_cvt_pk_f32_fp8(uu[k].x, true);  a[2] += d.x; a[3] += d.y;
                d = __builtin_amdgcn_cvt_pk_f32_fp8(uu[k].y, false); a[4] += d.x; a[5] += d.y;
                d = __builtin_amdgcn_cvt_pk_f32_fp8(uu[k].y, true);  a[6] += d.x; a[7] += d.y;
            }
        }
        c0 = n0; c1 = n1;
    }
    float invn = inv[n];
    float v[8];
    if (vc) {
        float4 s0 = *(const float4*)(selfp + (size_t)n * DO + chunk * 8);
        float4 s1 = *(const float4*)(selfp + (size_t)n * DO + chunk * 8 + 4);
        v[0] = a[0] * invn + s0.x; v[1] = a[1] * invn + s0.y;
        v[2] = a[2] * invn + s0.z; v[3] = a[3] * invn + s0.w;
        v[4] = a[4] * invn + s1.x; v[5] = a[5] * invn + s1.y;
        v[6] = a[6] * invn + s1.z; v[7] = a[7] * invn + s1.w;
    } else {
#pragma unroll
        for (int j = 0; j < 8; j++) v[j] = 0.f;
    }
    float mv = -INFINITY;
    if (vc) {
#pragma unroll
        for (int j = 0; j < 8; j++) mv = fmaxf(mv, v[j]);
    }
#pragma unroll
    for (int off = 1; off <= 4; off <<= 1) mv = fmaxf(mv, __shfl_xor(mv, off, 8));
    float es = 0.f;
    if (vc) {
#pragma unroll
        for (int j = 0; j < 8; j++) es += expf(v[j] - mv);
    }
#pragma unroll
    for (int off = 1; off <= 4; off <<= 1) es += __shfl_xor(es, off, 8);
    if (vc) {
        float ls = mv + logf(es);
        float4 o0, o1;
        o0.x = v[0] - ls; o0.y = v[1] - ls; o0.z = v[2] - ls; o0.w = v[3] - ls;
        o1.x = v[4] - ls; o1.y = v[5] - ls; o1.z = v[6] - ls; o1.w = v[7] - ls;
        *(float4*)(out + (size_t)n * DO + chunk * 8) = o0;
        *(float4*)(out + (size_t)n * DO + chunk * 8 + 4) = o1;
    }
}

extern "C" void kernel_launch(void* const* d_in, const int* in_sizes, int n_in,
                              void* d_out, int out_size, void* d_ws, size_t ws_size,
                              hipStream_t stream) {
    const float* x   = (const float*)d_in[0];
    const int*  ei   = (const int*)d_in[1];
    const float* W1l = (const float*)d_in[2];
    const float* b1  = (const float*)d_in[3];
    const float* W1r = (const float*)d_in[4];
    const float* W2l = (const float*)d_in[5];
    const float* b2  = (const float*)d_in[6];
    const float* W2r = (const float*)d_in[7];
    float* out = (float*)d_out;

    const int E = in_sizes[1] / 2;
    const int N = NN;
    const int* src = ei;
    const int* dst = ei + E;
    const int nbe = (E + EPB - 1) / EPB;
    const int nsetup = ((N + 1) * 32 + TPB_S - 1) / TPB_S;

    size_t off = 0;
    auto alloc = [&](size_t nf) { size_t o = off; off += (nf + 63) & ~(size_t)63; return o; };
    size_t o_bcur   = alloc(NBUCK);                     // int (counts, memset to 0)
    size_t o_eb     = alloc((size_t)NBUCK * CAP);       // int
    size_t o_col    = alloc((size_t)NBUCK * CAPP + 64); // int (padded CSR col + slack)
    size_t o_rowptr = alloc(N);                         // int
    size_t o_cnt    = alloc(N);                         // int
    size_t o_inv    = alloc(N);                         // f32
    size_t o_xb     = alloc((size_t)(N + 1) * 32);      // u32 (64 bf16/row, +dummy)
    size_t o_p2     = alloc((size_t)(N + 1) * 10);      // u32 (40 fp8/row, +dummy) = 4MB
    size_t o_selfp  = alloc((size_t)N * DO);            // f32
    size_t o_wb1    = alloc(16384 / 2);
    size_t o_wb2    = alloc(10240 / 2);
    (void)ws_size;

    float* ws = (float*)d_ws;
    int* bcur   = (int*)(ws + o_bcur);
    int* eb     = (int*)(ws + o_eb);
    int* col    = (int*)(ws + o_col);
    int* rowptr = (int*)(ws + o_rowptr);
    int* cnt    = (int*)(ws + o_cnt);
    float* inv  = ws + o_inv;
    unsigned* xb = (unsigned*)(ws + o_xb);
    unsigned* p2 = (unsigned*)(ws + o_p2);
    float* selfp = ws + o_selfp;
    unsigned short* WB1 = (unsigned short*)(ws + o_wb1);
    unsigned short* WB2 = (unsigned short*)(ws + o_wb2);

    hipMemsetAsync(bcur, 0, NBUCK * sizeof(int), stream);

    setup_scatter_kernel<<<nbe + nsetup, TPB_S, 0, stream>>>(
        x, W1l, W1r, W2l, W2r, xb, WB1, WB2, p2, src, dst, bcur, eb, nbe, E, N);

    bucket_fill_kernel<<<NBUCK, 256, 0, stream>>>(eb, bcur, rowptr, cnt, inv, col, N);

    agg_gemm12_kernel<<<(N + 63) / 64, 256, 0, stream>>>(
        xb, rowptr, cnt, inv, col, WB1, b1, WB2, b2, p2, selfp, N);

    agg2_softmax_kernel<<<(N * 8 + 255) / 256, 256, 0, stream>>>(p2, selfp, rowptr, cnt, inv, col, out, N);
}